// Round 7
// baseline (296.671 us; speedup 1.0000x reference)
//
#include <hip/hip_runtime.h>

// ---- problem geometry ----
#define M_TOTAL 16384          // B*L
#define N_DIM   1024           // D
#define K_DIM   1024
#define L_SEQ   4096
#define B_SZ    4
#define D_DIM   1024
#define CH      64             // scan chunk length
#define NCHUNK  (L_SEQ / CH)   // 64
#define NCHAN   (B_SZ * D_DIM) // 4096

// ---- GEMM tile ----
#define BM 128
#define BN 128
#define BK 32
#define NKT (K_DIM / BK)       // 32
#define TPB 512                // 8 waves: 2M x 4N, wave tile 64x32

typedef __attribute__((ext_vector_type(8))) short v8s;
typedef __attribute__((ext_vector_type(4))) float f32x4;

#define SB0()   __builtin_amdgcn_sched_barrier(0)
#define BAR()   __builtin_amdgcn_s_barrier()
#define WAITL0() do { asm volatile("s_waitcnt lgkmcnt(0)" ::: "memory"); SB0(); } while (0)
#define WAITV0() do { asm volatile("s_waitcnt vmcnt(0)"   ::: "memory"); SB0(); } while (0)
#define AS1 __attribute__((address_space(1)))
#define AS3 __attribute__((address_space(3)))

__device__ __forceinline__ ushort f2b(float f) {
  uint u = __float_as_uint(f);
  u += 0x7FFFu + ((u >> 16) & 1u);   // RNE (finite inputs)
  return (ushort)(u >> 16);
}
__device__ __forceinline__ float b2f(ushort u) {
  return __uint_as_float(((uint)u) << 16);
}

__global__ void cast_f32_bf16(const float* __restrict__ src, ushort* __restrict__ dst, int n4) {
  int i = blockIdx.x * blockDim.x + threadIdx.x;
  if (i >= n4) return;
  float4 v = reinterpret_cast<const float4*>(src)[i];
  ushort4 o = make_ushort4(f2b(v.x), f2b(v.y), f2b(v.z), f2b(v.w));
  reinterpret_cast<ushort4*>(dst)[i] = o;
}

__global__ void cast_w3(const float* __restrict__ s0, const float* __restrict__ s1,
                        const float* __restrict__ s2,
                        ushort* __restrict__ o0, ushort* __restrict__ o1, ushort* __restrict__ o2) {
  int i = blockIdx.x * blockDim.x + threadIdx.x;
  const float* s = (blockIdx.y == 0) ? s0 : (blockIdx.y == 1) ? s1 : s2;
  ushort* o      = (blockIdx.y == 0) ? o0 : (blockIdx.y == 1) ? o1 : o2;
  float4 v = reinterpret_cast<const float4*>(s)[i];
  ushort4 t = make_ushort4(f2b(v.x), f2b(v.y), f2b(v.z), f2b(v.w));
  reinterpret_cast<ushort4*>(o)[i] = t;
}

// gates: f = (1+e^-ip)/(2+e^-fp+e^-ip), i = 1-f, h~ = hp>=0 ? hp+0.5 : sigmoid(hp)
__device__ __forceinline__ void gates(float fp, float ip, float hp, float& a, float& v) {
  float Ef = __expf(-fp);
  float Ei = __expf(-ip);
  float r  = __builtin_amdgcn_rcpf(2.f + Ef + Ei);
  float f  = (1.f + Ei) * r;
  float i  = (1.f + Ef) * r;
  float ht = (hp >= 0.f) ? (hp + 0.5f) : __builtin_amdgcn_rcpf(1.f + __expf(-hp));
  a = f;
  v = i * ht;
}

struct Bset { v8s m[3][2]; };   // [gate][n-tile], all accesses compile-time-indexed

// Fused 3-GEMM: A via LDS (16 KiB dbuf, global_load_lds), B direct from L2 into
// registers (double-buffered one K-tile ahead). LDS pipe carries A only.
__launch_bounds__(TPB, 2)
__global__ void gemm_fused(const ushort* __restrict__ X,
                           const ushort* __restrict__ W0, const ushort* __restrict__ W1,
                           const ushort* __restrict__ W2,
                           const float* __restrict__ bfp, const float* __restrict__ bip,
                           const float* __restrict__ bhp,
                           uint* __restrict__ Pav)
{
  __shared__ ushort lds[2][BM * BK];   // A only: 2 x 8 KiB

  // W-panel-resident swizzle: xcd = id&7 owns m-band xcd*16..+15; n changes every 16 blocks
  const int id  = blockIdx.x;
  const int xcd = id & 7, j = id >> 3;
  const int m0 = (xcd * 16 + (j & 15)) * BM;
  const int n0 = (j >> 4) * BN;

  const int tid  = threadIdx.x;
  const int lane = tid & 63;
  const int w    = tid >> 6;          // 0..7
  const int wr   = w >> 2;            // 0..1 : 64-row strip
  const int wc   = w & 3;             // 0..3 : 32-col strip
  const int fr   = lane & 15, g = lane >> 4;

  // ---- A ds_read offsets (halfwords), XOR-swizzled: 16B slot g ^ ((row>>1)&3) ----
  int aoffh[4];
#pragma unroll
  for (int q = 0; q < 4; ++q) {
    int row = wr * 64 + q * 16 + fr;
    aoffh[q] = row * BK + ((g ^ ((row >> 1) & 3)) << 3);
  }

  // ---- A staging: 512 slots of 16B, 1/thread; inverse-swizzled global source ----
  const int r0 = tid >> 2;
  const int k16 = (tid & 3) ^ ((r0 >> 1) & 3);
  const ushort* gA = X + (size_t)(m0 + r0) * K_DIM + k16 * 8;
  const int dh = tid * 8;   // halfword dest (wave-uniform base + lane*16B: linear)

  auto stageA = [&](int buf, int kt) {
    __builtin_amdgcn_global_load_lds((const AS1 void*)(gA + kt * BK),
        (AS3 void*)(&lds[buf][0] + dh), 16, 0, 0);
  };

  // ---- B direct-load bases: per-lane contiguous 16B = exact MFMA B-fragment ----
  const int colb0 = n0 + wc * 32 + fr;        // ni=0
  const ushort* pB[3][2];
  pB[0][0] = W0 + (size_t)colb0 * K_DIM + g * 8;
  pB[0][1] = W0 + (size_t)(colb0 + 16) * K_DIM + g * 8;
  pB[1][0] = W1 + (size_t)colb0 * K_DIM + g * 8;
  pB[1][1] = W1 + (size_t)(colb0 + 16) * K_DIM + g * 8;
  pB[2][0] = W2 + (size_t)colb0 * K_DIM + g * 8;
  pB[2][1] = W2 + (size_t)(colb0 + 16) * K_DIM + g * 8;

  f32x4 acc[3][4][2] = {};
  Bset BA, BB;

#define LOADB(dst, kt)                                                        \
  do {                                                                        \
    _Pragma("unroll")                                                         \
    for (int z = 0; z < 3; ++z)                                               \
      _Pragma("unroll")                                                       \
      for (int ni = 0; ni < 2; ++ni)                                          \
        dst.m[z][ni] = *reinterpret_cast<const v8s*>(pB[z][ni] + (kt) * BK);  \
  } while (0)

  // prologue: stage A tile 0, load B tile 0
  stageA(0, 0);
  LOADB(BA, 0);
  WAITV0();
  BAR(); SB0();

#define TILE_BODY(bcur, bnext, t)                                             \
  do {                                                                        \
    const bool pf = ((t) + 1 < NKT);                                          \
    const int cur = (t) & 1;                                                  \
    if (pf) { LOADB(bnext, (t) + 1); stageA(cur ^ 1, (t) + 1); }              \
    SB0();                                                                    \
    v8s aF[4];                                                                \
    _Pragma("unroll")                                                         \
    for (int q = 0; q < 4; ++q)                                               \
      aF[q] = *reinterpret_cast<const v8s*>(&lds[cur][0] + aoffh[q]);         \
    SB0();                                                                    \
    WAITL0();                                                                 \
    __builtin_amdgcn_s_setprio(1);                                            \
    _Pragma("unroll")                                                         \
    for (int z = 0; z < 3; ++z)                                               \
      _Pragma("unroll")                                                       \
      for (int mi = 0; mi < 4; ++mi) {                                        \
        acc[z][mi][0] = __builtin_amdgcn_mfma_f32_16x16x32_bf16(              \
            aF[mi], bcur.m[z][0], acc[z][mi][0], 0, 0, 0);                    \
        acc[z][mi][1] = __builtin_amdgcn_mfma_f32_16x16x32_bf16(              \
            aF[mi], bcur.m[z][1], acc[z][mi][1], 0, 0, 0);                    \
      }                                                                       \
    __builtin_amdgcn_s_setprio(0);                                            \
    if (pf) { WAITV0(); BAR(); SB0(); }                                       \
  } while (0)

  for (int t = 0; t < NKT; t += 2) {
    TILE_BODY(BA, BB, t);
    TILE_BODY(BB, BA, t + 1);
  }
#undef TILE_BODY
#undef LOADB

  // epilogue: C/D layout col=lane&15, row=(lane>>4)*4+r  [m89-verified]
#pragma unroll
  for (int ni = 0; ni < 2; ++ni) {
    const int col = n0 + wc * 32 + ni * 16 + fr;
    const float vbf = bfp[col], vbi = bip[col], vbh = bhp[col];
#pragma unroll
    for (int mi = 0; mi < 4; ++mi) {
      const int row0 = m0 + wr * 64 + mi * 16 + g * 4;
#pragma unroll
      for (int r = 0; r < 4; ++r) {
        float a, v;
        gates(acc[0][mi][ni][r] + vbf, acc[1][mi][ni][r] + vbi, acc[2][mi][ni][r] + vbh, a, v);
        Pav[(size_t)(row0 + r) * N_DIM + col] = (uint)f2b(a) | ((uint)f2b(v) << 16);
      }
    }
  }
}

// pass1: 4 channels per thread (uint4 loads): per-chunk aggregate h_end = A*h_start + V
__global__ void scan_pass1(const uint4* __restrict__ Pav4,
                           float4* __restrict__ AggA, float4* __restrict__ AggV)
{
  int tid = blockIdx.x * blockDim.x + threadIdx.x;   // 65536
  int c4 = tid & 1023;
  int chunk = tid >> 10;
  int b = c4 >> 8;
  int d4 = c4 & 255;
  size_t base4 = ((size_t)b * L_SEQ + (size_t)chunk * CH) * (D_DIM / 4) + d4;
  float A0 = 1.f, A1 = 1.f, A2 = 1.f, A3 = 1.f;
  float V0 = 0.f, V1 = 0.f, V2 = 0.f, V3 = 0.f;
#pragma unroll 4
  for (int t = 0; t < CH; ++t) {
    uint4 u = Pav4[base4 + (size_t)t * (D_DIM / 4)];
    float a0 = b2f((ushort)(u.x & 0xFFFFu)), v0 = b2f((ushort)(u.x >> 16));
    float a1 = b2f((ushort)(u.y & 0xFFFFu)), v1 = b2f((ushort)(u.y >> 16));
    float a2 = b2f((ushort)(u.z & 0xFFFFu)), v2 = b2f((ushort)(u.z >> 16));
    float a3 = b2f((ushort)(u.w & 0xFFFFu)), v3 = b2f((ushort)(u.w >> 16));
    A0 *= a0; V0 = fmaf(a0, V0, v0);
    A1 *= a1; V1 = fmaf(a1, V1, v1);
    A2 *= a2; V2 = fmaf(a2, V2, v2);
    A3 *= a3; V3 = fmaf(a3, V3, v3);
  }
  AggA[(size_t)chunk * (NCHAN / 4) + c4] = make_float4(A0, A1, A2, A3);
  AggV[(size_t)chunk * (NCHAN / 4) + c4] = make_float4(V0, V1, V2, V3);
}

// mid: sequential combine across chunk aggregates, 4 channels per thread
__global__ void scan_mid(const float4* __restrict__ AggA, const float4* __restrict__ AggV,
                         float4* __restrict__ Start)
{
  int c4 = blockIdx.x * blockDim.x + threadIdx.x;   // 1024
  float4 h = make_float4(0.f, 0.f, 0.f, 0.f);
#pragma unroll
  for (int j = 0; j < NCHUNK; ++j) {
    float4 A = AggA[(size_t)j * (NCHAN / 4) + c4];
    float4 V = AggV[(size_t)j * (NCHAN / 4) + c4];
    Start[(size_t)j * (NCHAN / 4) + c4] = h;
    h.x = fmaf(A.x, h.x, V.x);
    h.y = fmaf(A.y, h.y, V.y);
    h.z = fmaf(A.z, h.z, V.z);
    h.w = fmaf(A.w, h.w, V.w);
  }
}

// pass2: replay each chunk with true carry, 4 channels per thread, float4 out
__global__ void scan_pass2(const uint4* __restrict__ Pav4,
                           const float4* __restrict__ Start, float4* __restrict__ out4)
{
  int tid = blockIdx.x * blockDim.x + threadIdx.x;   // 65536
  int c4 = tid & 1023;
  int chunk = tid >> 10;
  int b = c4 >> 8;
  int d4 = c4 & 255;
  size_t base4 = ((size_t)b * L_SEQ + (size_t)chunk * CH) * (D_DIM / 4) + d4;
  float4 h = Start[(size_t)chunk * (NCHAN / 4) + c4];
#pragma unroll 4
  for (int t = 0; t < CH; ++t) {
    size_t idx = base4 + (size_t)t * (D_DIM / 4);
    uint4 u = Pav4[idx];
    h.x = fmaf(b2f((ushort)(u.x & 0xFFFFu)), h.x, b2f((ushort)(u.x >> 16)));
    h.y = fmaf(b2f((ushort)(u.y & 0xFFFFu)), h.y, b2f((ushort)(u.y >> 16)));
    h.z = fmaf(b2f((ushort)(u.z & 0xFFFFu)), h.z, b2f((ushort)(u.z >> 16)));
    h.w = fmaf(b2f((ushort)(u.w & 0xFFFFu)), h.w, b2f((ushort)(u.w >> 16)));
    out4[idx] = h;
  }
}

extern "C" void kernel_launch(void* const* d_in, const int* in_sizes, int n_in,
                              void* d_out, int out_size, void* d_ws, size_t ws_size,
                              hipStream_t stream) {
  (void)in_sizes; (void)n_in; (void)out_size; (void)ws_size;
  const float* x  = (const float*)d_in[0];
  const float* Wf = (const float*)d_in[1];
  const float* bf = (const float*)d_in[2];
  const float* Wi = (const float*)d_in[3];
  const float* bi = (const float*)d_in[4];
  const float* Wh = (const float*)d_in[5];
  const float* bh = (const float*)d_in[6];

  // workspace (~107 MB)
  ushort* xb  = (ushort*)d_ws;                         // 33.5 MB
  ushort* wfb = xb  + (size_t)M_TOTAL * K_DIM;
  ushort* wib = wfb + (size_t)N_DIM * K_DIM;
  ushort* whb = wib + (size_t)N_DIM * K_DIM;
  uint*  Pav  = (uint*)(whb + (size_t)N_DIM * K_DIM);  // 67 MB packed (a,v)
  float* AggA  = (float*)(Pav + (size_t)M_TOTAL * N_DIM);
  float* AggV  = AggA + NCHAN * NCHUNK;
  float* Start = AggV + NCHAN * NCHUNK;

  cast_f32_bf16<<<(M_TOTAL * K_DIM / 4) / 256, 256, 0, stream>>>(x, xb, M_TOTAL * K_DIM / 4);
  cast_w3<<<dim3((N_DIM * K_DIM / 4) / 256, 3), 256, 0, stream>>>(Wf, Wi, Wh, wfb, wib, whb);

  gemm_fused<<<dim3((M_TOTAL / BM) * (N_DIM / BN)), TPB, 0, stream>>>(
      xb, wfb, wib, whb, bf, bi, bh, Pav);

  scan_pass1<<<(NCHAN / 4 * NCHUNK) / 256, 256, 0, stream>>>(
      (const uint4*)Pav, (float4*)AggA, (float4*)AggV);
  scan_mid<<<(NCHAN / 4) / 256, 256, 0, stream>>>(
      (const float4*)AggA, (const float4*)AggV, (float4*)Start);
  scan_pass2<<<(NCHAN / 4 * NCHUNK) / 256, 256, 0, stream>>>(
      (const uint4*)Pav, (const float4*)Start, (float4*)d_out);
}

// Round 9
// 225.666 us; speedup vs baseline: 1.3146x; 1.3146x over previous
//
#include <hip/hip_runtime.h>

// ---- problem geometry ----
#define M_TOTAL 16384          // B*L
#define N_DIM   1024           // D
#define K_DIM   1024
#define L_SEQ   4096
#define B_SZ    4
#define D_DIM   1024
#define CH      64             // scan chunk length
#define NCHUNK  (L_SEQ / CH)   // 64
#define NCHAN   (B_SZ * D_DIM) // 4096

// ---- GEMM tile (256x256, BK=32, 4-slot LDS ring, 8 waves 2Mx4N) ----
#define BM2 256
#define BN2 256
#define BK2 32
#define NT  (K_DIM / BK2)      // 32 K-tiles
#define GTPB 512

typedef __attribute__((ext_vector_type(8))) short v8s;
typedef __attribute__((ext_vector_type(4))) float f32x4;

#define SB0()   __builtin_amdgcn_sched_barrier(0)
#define BAR()   __builtin_amdgcn_s_barrier()
#define WAITL0() do { asm volatile("s_waitcnt lgkmcnt(0)" ::: "memory"); SB0(); } while (0)
#define WAITV4() do { asm volatile("s_waitcnt vmcnt(4)"   ::: "memory"); SB0(); } while (0)
#define WAITV0() do { asm volatile("s_waitcnt vmcnt(0)"   ::: "memory"); SB0(); } while (0)
#define AS1 __attribute__((address_space(1)))
#define AS3 __attribute__((address_space(3)))

__device__ __forceinline__ ushort f2b(float f) {
  uint u = __float_as_uint(f);
  u += 0x7FFFu + ((u >> 16) & 1u);   // RNE (finite inputs)
  return (ushort)(u >> 16);
}
__device__ __forceinline__ float b2f(ushort u) {
  return __uint_as_float(((uint)u) << 16);
}

__global__ void cast_f32_bf16(const float* __restrict__ src, ushort* __restrict__ dst, int n4) {
  int i = blockIdx.x * blockDim.x + threadIdx.x;
  if (i >= n4) return;
  float4 v = reinterpret_cast<const float4*>(src)[i];
  ushort4 o = make_ushort4(f2b(v.x), f2b(v.y), f2b(v.z), f2b(v.w));
  reinterpret_cast<ushort4*>(dst)[i] = o;
}

__global__ void cast_w3(const float* __restrict__ s0, const float* __restrict__ s1,
                        const float* __restrict__ s2,
                        ushort* __restrict__ o0, ushort* __restrict__ o1, ushort* __restrict__ o2) {
  int i = blockIdx.x * blockDim.x + threadIdx.x;
  const float* s = (blockIdx.y == 0) ? s0 : (blockIdx.y == 1) ? s1 : s2;
  ushort* o      = (blockIdx.y == 0) ? o0 : (blockIdx.y == 1) ? o1 : o2;
  float4 v = reinterpret_cast<const float4*>(s)[i];
  ushort4 t = make_ushort4(f2b(v.x), f2b(v.y), f2b(v.z), f2b(v.w));
  reinterpret_cast<ushort4*>(o)[i] = t;
}

// gates: f = (1+e^-ip)/(2+e^-fp+e^-ip), i = 1-f, h~ = hp>=0 ? hp+0.5 : sigmoid(hp)
__device__ __forceinline__ void gates(float fp, float ip, float hp, float& a, float& v) {
  float Ef = __expf(-fp);
  float Ei = __expf(-ip);
  float r  = __builtin_amdgcn_rcpf(2.f + Ef + Ei);
  float f  = (1.f + Ei) * r;
  float i  = (1.f + Ef) * r;
  float ht = (hp >= 0.f) ? (hp + 0.5f) : __builtin_amdgcn_rcpf(1.f + __expf(-hp));
  a = f;
  v = i * ht;
}

// 256x256 single-gate GEMM, 2 phases per K-tile, 4-slot LDS ring, depth-2 K-tile
// prefetch with wait-then-barrier counted vmcnt. One gate per block (wgid decode).
__launch_bounds__(GTPB, 2)
__global__ void gemm256(const ushort* __restrict__ X,
                        const ushort* __restrict__ W0, const ushort* __restrict__ W1,
                        const ushort* __restrict__ W2,
                        const float* __restrict__ bfp, const float* __restrict__ bip,
                        const float* __restrict__ bhp,
                        ushort* __restrict__ P0, ushort* __restrict__ P1, ushort* __restrict__ P2)
{
  __shared__ ushort lds[4][16384];   // 4 ring slots x (A 16KB | B 16KB) = 128 KiB

  // bijective XCD swizzle over 768 blocks; within XCD: m fastest (W panel L2-hot)
  const int q  = blockIdx.x;
  const int wg = (q & 7) * 96 + (q >> 3);
  const int z  = wg >> 8;            // gate 0..2
  const int r_ = wg & 255;
  const int n0 = (r_ >> 6) * BN2;
  const int m0 = (r_ & 63) * BM2;

  const ushort* W = (z == 0) ? W0 : (z == 1) ? W1 : W2;
  ushort*       P = (z == 0) ? P0 : (z == 1) ? P1 : P2;
  const float*  bias = (z == 0) ? bfp : (z == 1) ? bip : bhp;

  const int tid  = threadIdx.x;
  const int lane = tid & 63;
  const int w    = tid >> 6;          // 0..7
  const int wr   = w >> 2;            // 0..1 : 128-row strip
  const int wc   = w & 3;             // 0..3 : 64-col strip
  const int fr   = lane & 15, g = lane >> 4;

  // ---- swizzled ds_read offsets (halfwords): row*32 + (g ^ ((row>>1)&3))*8 ----
  int aoffh[8], boffh[4];
#pragma unroll
  for (int m = 0; m < 8; ++m) {
    int row = wr * 128 + m * 16 + fr;
    aoffh[m] = row * 32 + ((g ^ ((row >> 1) & 3)) << 3);
  }
#pragma unroll
  for (int n = 0; n < 4; ++n) {
    int row = wc * 64 + n * 16 + fr;
    boffh[n] = 8192 + row * 32 + ((g ^ ((row >> 1) & 3)) << 3);
  }

  // ---- staging: A slots {tid, 512+tid}, B slots {tid, 512+tid} (lane-contiguous) ----
  const int rA0 = tid >> 2,        qA0 = (tid & 3) ^ ((rA0 >> 1) & 3);
  const int rA1 = 128 + (tid >> 2), qA1 = (tid & 3) ^ ((rA1 >> 1) & 3);
  const ushort* gA0 = X + (size_t)(m0 + rA0) * K_DIM + qA0 * 8;
  const ushort* gA1 = X + (size_t)(m0 + rA1) * K_DIM + qA1 * 8;
  const ushort* gB0 = W + (size_t)(n0 + rA0) * K_DIM + qA0 * 8;
  const ushort* gB1 = W + (size_t)(n0 + rA1) * K_DIM + qA1 * 8;
  const int dh0 = tid * 8, dh1 = (512 + tid) * 8;   // halfword dest offsets

  auto stageA = [&](int slot, int kt) {
    __builtin_amdgcn_global_load_lds((const AS1 void*)(gA0 + kt * BK2),
        (AS3 void*)(&lds[slot][dh0]), 16, 0, 0);
    __builtin_amdgcn_global_load_lds((const AS1 void*)(gA1 + kt * BK2),
        (AS3 void*)(&lds[slot][dh1]), 16, 0, 0);
  };
  auto stageB = [&](int slot, int kt) {
    __builtin_amdgcn_global_load_lds((const AS1 void*)(gB0 + kt * BK2),
        (AS3 void*)(&lds[slot][8192 + dh0]), 16, 0, 0);
    __builtin_amdgcn_global_load_lds((const AS1 void*)(gB1 + kt * BK2),
        (AS3 void*)(&lds[slot][8192 + dh1]), 16, 0, 0);
  };

  f32x4 acc[8][4] = {};

  // prologue: stage K-tiles 0 and 1 (A0,B0,A1,B1 -> oldest 4 = tile 0)
  stageA(0, 0); stageB(0, 0);
  stageA(1, 1); stageB(1, 1);
  WAITV4();   // tile 0's 4 loads landed (tile 1's in flight)
  BAR(); SB0();

  for (int t = 0; t < NT; ++t) {
    const int slot = t & 3;
    const bool pf = (t + 2 < NT);
    v8s aF[4], bF[4];

    // ---- phase 0: mi 0..3 (reads guarded by previous tile's tail wait+BAR) ----
#pragma unroll
    for (int n = 0; n < 4; ++n) bF[n] = *reinterpret_cast<const v8s*>(&lds[slot][boffh[n]]);
#pragma unroll
    for (int m = 0; m < 4; ++m) aF[m] = *reinterpret_cast<const v8s*>(&lds[slot][aoffh[m]]);
    if (pf) stageA((t + 2) & 3, t + 2);
    SB0(); BAR(); WAITL0();
    __builtin_amdgcn_s_setprio(1);
#pragma unroll
    for (int m = 0; m < 4; ++m)
#pragma unroll
      for (int n = 0; n < 4; ++n)
        acc[m][n] = __builtin_amdgcn_mfma_f32_16x16x32_bf16(aF[m], bF[n], acc[m][n], 0, 0, 0);
    __builtin_amdgcn_s_setprio(0);
    BAR(); SB0();

    // ---- phase 1: mi 4..7 (bF reused from registers) ----
#pragma unroll
    for (int m = 0; m < 4; ++m) aF[m] = *reinterpret_cast<const v8s*>(&lds[slot][aoffh[4 + m]]);
    if (pf) stageB((t + 2) & 3, t + 2);
    SB0(); BAR(); WAITL0();
    __builtin_amdgcn_s_setprio(1);
#pragma unroll
    for (int m = 0; m < 4; ++m)
#pragma unroll
      for (int n = 0; n < 4; ++n)
        acc[4 + m][n] = __builtin_amdgcn_mfma_f32_16x16x32_bf16(aF[m], bF[n], acc[4 + m][n], 0, 0, 0);
    __builtin_amdgcn_s_setprio(0);
    // tail: guard next K-tile's reads (wait own count, THEN barrier -> collective)
    if (t + 1 < NT) {
      if (pf) { WAITV4(); } else { WAITV0(); }
      BAR(); SB0();
    }
  }

  // epilogue: C/D layout col=lane&15, row=(lane>>4)*4+r  [m89-verified]
#pragma unroll
  for (int m = 0; m < 8; ++m) {
    const int row0 = m0 + wr * 128 + m * 16 + g * 4;
#pragma unroll
    for (int n = 0; n < 4; ++n) {
      const int col = n0 + wc * 64 + n * 16 + fr;
      const float bv = bias[col];
#pragma unroll
      for (int r = 0; r < 4; ++r)
        P[(size_t)(row0 + r) * N_DIM + col] = f2b(acc[m][n][r] + bv);
    }
  }
}

// pass1 (gate-fused): read 3 bf16 preacts, compute gates, per-chunk aggregate
__global__ void scan_pass1g(const ushort4* __restrict__ Pf4, const ushort4* __restrict__ Pi4,
                            const ushort4* __restrict__ Ph4,
                            const float* __restrict__ bfp, const float* __restrict__ bip,
                            const float* __restrict__ bhp,
                            float4* __restrict__ AggA, float4* __restrict__ AggV)
{
  int tid = blockIdx.x * blockDim.x + threadIdx.x;   // 65536
  int c4 = tid & 1023;
  int chunk = tid >> 10;
  int b = c4 >> 8;
  int d4 = c4 & 255;
  int d0 = d4 * 4;
  float bf0 = bfp[d0], bf1 = bfp[d0 + 1], bf2 = bfp[d0 + 2], bf3 = bfp[d0 + 3];
  float bi0 = bip[d0], bi1 = bip[d0 + 1], bi2 = bip[d0 + 2], bi3 = bip[d0 + 3];
  float bh0 = bhp[d0], bh1 = bhp[d0 + 1], bh2 = bhp[d0 + 2], bh3 = bhp[d0 + 3];
  size_t base = ((size_t)b * L_SEQ + (size_t)chunk * CH) * 256 + d4;
  float A0 = 1.f, A1 = 1.f, A2 = 1.f, A3 = 1.f;
  float V0 = 0.f, V1 = 0.f, V2 = 0.f, V3 = 0.f;
#pragma unroll 2
  for (int t = 0; t < CH; ++t) {
    size_t idx = base + (size_t)t * 256;
    ushort4 uf = Pf4[idx], ui = Pi4[idx], uh = Ph4[idx];
    float a, v;
    gates(b2f(uf.x) + bf0, b2f(ui.x) + bi0, b2f(uh.x) + bh0, a, v); A0 *= a; V0 = fmaf(a, V0, v);
    gates(b2f(uf.y) + bf1, b2f(ui.y) + bi1, b2f(uh.y) + bh1, a, v); A1 *= a; V1 = fmaf(a, V1, v);
    gates(b2f(uf.z) + bf2, b2f(ui.z) + bi2, b2f(uh.z) + bh2, a, v); A2 *= a; V2 = fmaf(a, V2, v);
    gates(b2f(uf.w) + bf3, b2f(ui.w) + bi3, b2f(uh.w) + bh3, a, v); A3 *= a; V3 = fmaf(a, V3, v);
  }
  AggA[(size_t)chunk * (NCHAN / 4) + c4] = make_float4(A0, A1, A2, A3);
  AggV[(size_t)chunk * (NCHAN / 4) + c4] = make_float4(V0, V1, V2, V3);
}

// mid: sequential combine across chunk aggregates, 4 channels per thread
__global__ void scan_mid(const float4* __restrict__ AggA, const float4* __restrict__ AggV,
                         float4* __restrict__ Start)
{
  int c4 = blockIdx.x * blockDim.x + threadIdx.x;   // 1024
  float4 h = make_float4(0.f, 0.f, 0.f, 0.f);
#pragma unroll
  for (int j = 0; j < NCHUNK; ++j) {
    float4 A = AggA[(size_t)j * (NCHAN / 4) + c4];
    float4 V = AggV[(size_t)j * (NCHAN / 4) + c4];
    Start[(size_t)j * (NCHAN / 4) + c4] = h;
    h.x = fmaf(A.x, h.x, V.x);
    h.y = fmaf(A.y, h.y, V.y);
    h.z = fmaf(A.z, h.z, V.z);
    h.w = fmaf(A.w, h.w, V.w);
  }
}

// pass2 (gate-fused): replay each chunk with true carry, write h (f32)
__global__ void scan_pass2g(const ushort4* __restrict__ Pf4, const ushort4* __restrict__ Pi4,
                            const ushort4* __restrict__ Ph4,
                            const float* __restrict__ bfp, const float* __restrict__ bip,
                            const float* __restrict__ bhp,
                            const float4* __restrict__ Start, float4* __restrict__ out4)
{
  int tid = blockIdx.x * blockDim.x + threadIdx.x;   // 65536
  int c4 = tid & 1023;
  int chunk = tid >> 10;
  int b = c4 >> 8;
  int d4 = c4 & 255;
  int d0 = d4 * 4;
  float bf0 = bfp[d0], bf1 = bfp[d0 + 1], bf2 = bfp[d0 + 2], bf3 = bfp[d0 + 3];
  float bi0 = bip[d0], bi1 = bip[d0 + 1], bi2 = bip[d0 + 2], bi3 = bip[d0 + 3];
  float bh0 = bhp[d0], bh1 = bhp[d0 + 1], bh2 = bhp[d0 + 2], bh3 = bhp[d0 + 3];
  size_t base = ((size_t)b * L_SEQ + (size_t)chunk * CH) * 256 + d4;
  float4 h = Start[(size_t)chunk * (NCHAN / 4) + c4];
#pragma unroll 2
  for (int t = 0; t < CH; ++t) {
    size_t idx = base + (size_t)t * 256;
    ushort4 uf = Pf4[idx], ui = Pi4[idx], uh = Ph4[idx];
    float a, v;
    gates(b2f(uf.x) + bf0, b2f(ui.x) + bi0, b2f(uh.x) + bh0, a, v); h.x = fmaf(a, h.x, v);
    gates(b2f(uf.y) + bf1, b2f(ui.y) + bi1, b2f(uh.y) + bh1, a, v); h.y = fmaf(a, h.y, v);
    gates(b2f(uf.z) + bf2, b2f(ui.z) + bi2, b2f(uh.z) + bh2, a, v); h.z = fmaf(a, h.z, v);
    gates(b2f(uf.w) + bf3, b2f(ui.w) + bi3, b2f(uh.w) + bh3, a, v); h.w = fmaf(a, h.w, v);
    out4[idx] = h;
  }
}

extern "C" void kernel_launch(void* const* d_in, const int* in_sizes, int n_in,
                              void* d_out, int out_size, void* d_ws, size_t ws_size,
                              hipStream_t stream) {
  (void)in_sizes; (void)n_in; (void)out_size; (void)ws_size;
  const float* x  = (const float*)d_in[0];
  const float* Wf = (const float*)d_in[1];
  const float* bf = (const float*)d_in[2];
  const float* Wi = (const float*)d_in[3];
  const float* bi = (const float*)d_in[4];
  const float* Wh = (const float*)d_in[5];
  const float* bh = (const float*)d_in[6];

  // workspace (~143 MB)
  ushort* xb  = (ushort*)d_ws;                         // 33.5 MB
  ushort* wfb = xb  + (size_t)M_TOTAL * K_DIM;
  ushort* wib = wfb + (size_t)N_DIM * K_DIM;
  ushort* whb = wib + (size_t)N_DIM * K_DIM;
  ushort* Pf  = whb + (size_t)N_DIM * K_DIM;           // 33.5 MB each, bf16 preacts
  ushort* Pi  = Pf  + (size_t)M_TOTAL * N_DIM;
  ushort* Ph  = Pi  + (size_t)M_TOTAL * N_DIM;
  float*  AggA  = (float*)(Ph + (size_t)M_TOTAL * N_DIM);
  float*  AggV  = AggA + NCHAN * NCHUNK;
  float*  Start = AggV + NCHAN * NCHUNK;

  cast_f32_bf16<<<(M_TOTAL * K_DIM / 4) / 256, 256, 0, stream>>>(x, xb, M_TOTAL * K_DIM / 4);
  cast_w3<<<dim3((N_DIM * K_DIM / 4) / 256, 3), 256, 0, stream>>>(Wf, Wi, Wh, wfb, wib, whb);

  gemm256<<<dim3(3 * (M_TOTAL / BM2) * (N_DIM / BN2)), GTPB, 0, stream>>>(
      xb, wfb, wib, whb, bf, bi, bh, Pf, Pi, Ph);

  scan_pass1g<<<(NCHAN / 4 * NCHUNK) / 256, 256, 0, stream>>>(
      (const ushort4*)Pf, (const ushort4*)Pi, (const ushort4*)Ph,
      bf, bi, bh, (float4*)AggA, (float4*)AggV);
  scan_mid<<<(NCHAN / 4) / 256, 256, 0, stream>>>(
      (const float4*)AggA, (const float4*)AggV, (float4*)Start);
  scan_pass2g<<<(NCHAN / 4 * NCHUNK) / 256, 256, 0, stream>>>(
      (const ushort4*)Pf, (const ushort4*)Pi, (const ushort4*)Ph,
      bf, bi, bh, (const float4*)Start, (float4*)d_out);
}

// Round 10
// 176.354 us; speedup vs baseline: 1.6822x; 1.2796x over previous
//
#include <hip/hip_runtime.h>

// ---- problem geometry ----
#define M_TOTAL 16384          // B*L
#define N_DIM   1024           // D
#define K_DIM   1024
#define L_SEQ   4096
#define B_SZ    4
#define D_DIM   1024
#define CH      64             // scan chunk length
#define NCHUNK  (L_SEQ / CH)   // 64
#define NCHAN   (B_SZ * D_DIM) // 4096

// ---- GEMM tile ----
#define BM 128
#define BN 128
#define BK 64
#define NKT (K_DIM / BK)       // 16
#define TPB 512                // 8 waves: 2M x 4N, wave tile 64x32

typedef __attribute__((ext_vector_type(8))) short v8s;
typedef __attribute__((ext_vector_type(4))) float f32x4;

#define SB0()   __builtin_amdgcn_sched_barrier(0)
#define BAR()   __builtin_amdgcn_s_barrier()
#define WAITL0() do { asm volatile("s_waitcnt lgkmcnt(0)" ::: "memory"); SB0(); } while (0)
#define WAITL4() do { asm volatile("s_waitcnt lgkmcnt(4)" ::: "memory"); SB0(); } while (0)
#define WAITV0() do { asm volatile("s_waitcnt vmcnt(0)"   ::: "memory"); SB0(); } while (0)
#define AS1 __attribute__((address_space(1)))
#define AS3 __attribute__((address_space(3)))

__device__ __forceinline__ ushort f2b(float f) {
  uint u = __float_as_uint(f);
  u += 0x7FFFu + ((u >> 16) & 1u);   // RNE (finite inputs)
  return (ushort)(u >> 16);
}
__device__ __forceinline__ float b2f(ushort u) {
  return __uint_as_float(((uint)u) << 16);
}

__global__ void cast_f32_bf16(const float* __restrict__ src, ushort* __restrict__ dst, int n4) {
  int i = blockIdx.x * blockDim.x + threadIdx.x;
  if (i >= n4) return;
  float4 v = reinterpret_cast<const float4*>(src)[i];
  ushort4 o = make_ushort4(f2b(v.x), f2b(v.y), f2b(v.z), f2b(v.w));
  reinterpret_cast<ushort4*>(dst)[i] = o;
}

__global__ void cast_w3(const float* __restrict__ s0, const float* __restrict__ s1,
                        const float* __restrict__ s2,
                        ushort* __restrict__ o0, ushort* __restrict__ o1, ushort* __restrict__ o2) {
  int i = blockIdx.x * blockDim.x + threadIdx.x;
  const float* s = (blockIdx.y == 0) ? s0 : (blockIdx.y == 1) ? s1 : s2;
  ushort* o      = (blockIdx.y == 0) ? o0 : (blockIdx.y == 1) ? o1 : o2;
  float4 v = reinterpret_cast<const float4*>(s)[i];
  ushort4 t = make_ushort4(f2b(v.x), f2b(v.y), f2b(v.z), f2b(v.w));
  reinterpret_cast<ushort4*>(o)[i] = t;
}

// gates: f = (1+e^-ip)/(2+e^-fp+e^-ip), i = 1-f, h~ = hp>=0 ? hp+0.5 : sigmoid(hp)
__device__ __forceinline__ void gates(float fp, float ip, float hp, float& a, float& v) {
  float Ef = __expf(-fp);
  float Ei = __expf(-ip);
  float r  = __builtin_amdgcn_rcpf(2.f + Ef + Ei);
  float f  = (1.f + Ei) * r;
  float i  = (1.f + Ef) * r;
  float ht = (hp >= 0.f) ? (hp + 0.5f) : __builtin_amdgcn_rcpf(1.f + __expf(-hp));
  a = f;
  v = i * ht;
}

// Fused 3-GEMM (R5 structure, measured 125.4 us): BK=64, 2 LDS dbuf, one barrier
// + one vmcnt(0) per K-tile, counted-lgkm 3-phase ladder. New: L2-band swizzle
// (8 m-tiles per XCD sub-band -> X panel 2MB + W 2.25MB < 4MB L2/XCD).
__launch_bounds__(TPB, 2)
__global__ void gemm_fused(const ushort* __restrict__ X,
                           const ushort* __restrict__ W0, const ushort* __restrict__ W1,
                           const ushort* __restrict__ W2,
                           const float* __restrict__ bfp, const float* __restrict__ bip,
                           const float* __restrict__ bhp,
                           uint* __restrict__ Pav)
{
  __shared__ ushort lds[2][4][BM * BK];   // [buf][A,Bf,Bi,Bh]  2 x 64 KiB = 128 KiB

  // bijective XCD swizzle, 1024 blocks: XCD x owns m-tiles [x*16, x*16+16);
  // within XCD, sub-band of 8 m-tiles with n fastest (X band L2-resident)
  const int id  = blockIdx.x;
  const int x_  = id & 7;            // XCD
  const int k_  = id >> 3;           // 0..127
  const int sub = k_ >> 6;           // 0..1
  const int l2_ = k_ & 63;
  const int n0 = (l2_ & 7) * BN;
  const int m0 = (x_ * 16 + sub * 8 + (l2_ >> 3)) * BM;

  const int tid  = threadIdx.x;
  const int lane = tid & 63;
  const int w    = tid >> 6;          // 0..7
  const int wr   = w >> 2;            // 0..1 : 64-row strip
  const int wc   = w & 3;             // 0..3 : 32-col strip
  const int fr   = lane & 15, g = lane >> 4;

  // ---- swizzled ds_read offsets (halfwords): 16B slot (ks*4+g) ^ (row&7) ----
  int aoffh[4][2], boffh[2][2];
#pragma unroll
  for (int q = 0; q < 4; ++q)
#pragma unroll
    for (int ks = 0; ks < 2; ++ks) {
      int row = wr * 64 + q * 16 + fr;
      aoffh[q][ks] = row * BK + (((ks * 4 + g) ^ (row & 7)) << 3);
    }
#pragma unroll
  for (int n = 0; n < 2; ++n)
#pragma unroll
    for (int ks = 0; ks < 2; ++ks) {
      int row = wc * 32 + n * 16 + fr;
      boffh[n][ks] = row * BK + (((ks * 4 + g) ^ (row & 7)) << 3);
    }

  // ---- staging: 2 x 16B slots per matrix per thread; inverse-swizzled source ----
  const int s0 = tid, s1 = 512 + tid;
  const int r0 = s0 >> 3, k0 = (s0 & 7) ^ (r0 & 7);
  const int r1 = s1 >> 3, k1 = (s1 & 7) ^ (r1 & 7);
  const int d0 = s0 * 8, d1 = s1 * 8;   // halfword dest offsets

  const ushort* gsrc[4][2];
  gsrc[0][0] = X  + (size_t)(m0 + r0) * K_DIM + k0 * 8;
  gsrc[0][1] = X  + (size_t)(m0 + r1) * K_DIM + k1 * 8;
  gsrc[1][0] = W0 + (size_t)(n0 + r0) * K_DIM + k0 * 8;
  gsrc[1][1] = W0 + (size_t)(n0 + r1) * K_DIM + k1 * 8;
  gsrc[2][0] = W1 + (size_t)(n0 + r0) * K_DIM + k0 * 8;
  gsrc[2][1] = W1 + (size_t)(n0 + r1) * K_DIM + k1 * 8;
  gsrc[3][0] = W2 + (size_t)(n0 + r0) * K_DIM + k0 * 8;
  gsrc[3][1] = W2 + (size_t)(n0 + r1) * K_DIM + k1 * 8;

  auto issue = [&](int buf, int mat, int kt, int j) {
    const ushort* s_ = gsrc[mat][j] + kt * BK;
    __builtin_amdgcn_global_load_lds((const AS1 void*)s_,
        (AS3 void*)(&lds[buf][mat][j ? d1 : d0]), 16, 0, 0);
  };

  f32x4 acc[3][4][2] = {};

  // prologue: stage tile 0 fully, drain, barrier
#pragma unroll
  for (int mat = 0; mat < 4; ++mat) { issue(0, mat, 0, 0); issue(0, mat, 0, 1); }
  WAITV0();
  BAR(); SB0();

  int cur = 0;
  for (int t = 0; t < NKT; ++t) {
    const bool pf = (t + 1 < NKT);
    const ushort* rb = &lds[cur][0][0];
    v8s aF[4][2], bA[2][2], bB[2][2];

    // ---- issue group 1: aF + bA<-B0  (12 ds_reads) ----
#pragma unroll
    for (int q = 0; q < 4; ++q)
#pragma unroll
      for (int ks = 0; ks < 2; ++ks)
        aF[q][ks] = *reinterpret_cast<const v8s*>(rb + aoffh[q][ks]);
#pragma unroll
    for (int n = 0; n < 2; ++n)
#pragma unroll
      for (int ks = 0; ks < 2; ++ks)
        bA[n][ks] = *reinterpret_cast<const v8s*>(rb + 1 * BM * BK + boffh[n][ks]);
    SB0();
    // stage tile t+1 into cur^1 (safe: cur^1 last read in tile t-1, pre-barrier)
    if (pf) {
#pragma unroll
      for (int mat = 0; mat < 4; ++mat) { issue(cur ^ 1, mat, t + 1, 0); issue(cur ^ 1, mat, t + 1, 1); }
    }
    SB0();
    // ---- issue group 2: bB<-B1 (4 ds_reads)  [outstanding: 16] ----
#pragma unroll
    for (int n = 0; n < 2; ++n)
#pragma unroll
      for (int ks = 0; ks < 2; ++ks)
        bB[n][ks] = *reinterpret_cast<const v8s*>(rb + 2 * BM * BK + boffh[n][ks]);
    SB0();
    WAITL4();   // aF + bA landed; bB in flight
    __builtin_amdgcn_s_setprio(1);
#pragma unroll
    for (int ks = 0; ks < 2; ++ks)
#pragma unroll
      for (int mi = 0; mi < 4; ++mi) {
        acc[0][mi][0] = __builtin_amdgcn_mfma_f32_16x16x32_bf16(aF[mi][ks], bA[0][ks], acc[0][mi][0], 0, 0, 0);
        acc[0][mi][1] = __builtin_amdgcn_mfma_f32_16x16x32_bf16(aF[mi][ks], bA[1][ks], acc[0][mi][1], 0, 0, 0);
      }
    __builtin_amdgcn_s_setprio(0);
    // ---- issue group 3: bA<-B2 (4 ds_reads)  [outstanding: 8] ----
#pragma unroll
    for (int n = 0; n < 2; ++n)
#pragma unroll
      for (int ks = 0; ks < 2; ++ks)
        bA[n][ks] = *reinterpret_cast<const v8s*>(rb + 3 * BM * BK + boffh[n][ks]);
    SB0();
    WAITL4();   // bB landed; bA(B2) in flight
    __builtin_amdgcn_s_setprio(1);
#pragma unroll
    for (int ks = 0; ks < 2; ++ks)
#pragma unroll
      for (int mi = 0; mi < 4; ++mi) {
        acc[1][mi][0] = __builtin_amdgcn_mfma_f32_16x16x32_bf16(aF[mi][ks], bB[0][ks], acc[1][mi][0], 0, 0, 0);
        acc[1][mi][1] = __builtin_amdgcn_mfma_f32_16x16x32_bf16(aF[mi][ks], bB[1][ks], acc[1][mi][1], 0, 0, 0);
      }
    __builtin_amdgcn_s_setprio(0);
    WAITL0();   // bA(B2) landed
    __builtin_amdgcn_s_setprio(1);
#pragma unroll
    for (int ks = 0; ks < 2; ++ks)
#pragma unroll
      for (int mi = 0; mi < 4; ++mi) {
        acc[2][mi][0] = __builtin_amdgcn_mfma_f32_16x16x32_bf16(aF[mi][ks], bA[0][ks], acc[2][mi][0], 0, 0, 0);
        acc[2][mi][1] = __builtin_amdgcn_mfma_f32_16x16x32_bf16(aF[mi][ks], bA[1][ks], acc[2][mi][1], 0, 0, 0);
      }
    __builtin_amdgcn_s_setprio(0);

    // ---- tile boundary: single drain + single barrier (wait-then-barrier) ----
    if (pf) {
      WAITV0();   // t+1's 8 loads issued ~a full tile ago -> near-free
      BAR(); SB0();
      cur ^= 1;
    }
  }

  // epilogue: C/D layout col=lane&15, row=(lane>>4)*4+r  [m89-verified]
#pragma unroll
  for (int ni = 0; ni < 2; ++ni) {
    const int col = n0 + wc * 32 + ni * 16 + fr;
    const float vbf = bfp[col], vbi = bip[col], vbh = bhp[col];
#pragma unroll
    for (int mi = 0; mi < 4; ++mi) {
      const int row0 = m0 + wr * 64 + mi * 16 + g * 4;
#pragma unroll
      for (int r = 0; r < 4; ++r) {
        float a, v;
        gates(acc[0][mi][ni][r] + vbf, acc[1][mi][ni][r] + vbi, acc[2][mi][ni][r] + vbh, a, v);
        Pav[(size_t)(row0 + r) * N_DIM + col] = (uint)f2b(a) | ((uint)f2b(v) << 16);
      }
    }
  }
}

// pass1: 4 channels per thread (uint4 loads): per-chunk aggregate h_end = A*h_start + V
__global__ void scan_pass1(const uint4* __restrict__ Pav4,
                           float4* __restrict__ AggA, float4* __restrict__ AggV)
{
  int tid = blockIdx.x * blockDim.x + threadIdx.x;   // 65536
  int c4 = tid & 1023;
  int chunk = tid >> 10;
  int b = c4 >> 8;
  int d4 = c4 & 255;
  size_t base4 = ((size_t)b * L_SEQ + (size_t)chunk * CH) * (D_DIM / 4) + d4;
  float A0 = 1.f, A1 = 1.f, A2 = 1.f, A3 = 1.f;
  float V0 = 0.f, V1 = 0.f, V2 = 0.f, V3 = 0.f;
#pragma unroll 4
  for (int t = 0; t < CH; ++t) {
    uint4 u = Pav4[base4 + (size_t)t * (D_DIM / 4)];
    float a0 = b2f((ushort)(u.x & 0xFFFFu)), v0 = b2f((ushort)(u.x >> 16));
    float a1 = b2f((ushort)(u.y & 0xFFFFu)), v1 = b2f((ushort)(u.y >> 16));
    float a2 = b2f((ushort)(u.z & 0xFFFFu)), v2 = b2f((ushort)(u.z >> 16));
    float a3 = b2f((ushort)(u.w & 0xFFFFu)), v3 = b2f((ushort)(u.w >> 16));
    A0 *= a0; V0 = fmaf(a0, V0, v0);
    A1 *= a1; V1 = fmaf(a1, V1, v1);
    A2 *= a2; V2 = fmaf(a2, V2, v2);
    A3 *= a3; V3 = fmaf(a3, V3, v3);
  }
  AggA[(size_t)chunk * (NCHAN / 4) + c4] = make_float4(A0, A1, A2, A3);
  AggV[(size_t)chunk * (NCHAN / 4) + c4] = make_float4(V0, V1, V2, V3);
}

// mid: sequential combine across chunk aggregates, 4 channels per thread
__global__ void scan_mid(const float4* __restrict__ AggA, const float4* __restrict__ AggV,
                         float4* __restrict__ Start)
{
  int c4 = blockIdx.x * blockDim.x + threadIdx.x;   // 1024
  float4 h = make_float4(0.f, 0.f, 0.f, 0.f);
#pragma unroll
  for (int j = 0; j < NCHUNK; ++j) {
    float4 A = AggA[(size_t)j * (NCHAN / 4) + c4];
    float4 V = AggV[(size_t)j * (NCHAN / 4) + c4];
    Start[(size_t)j * (NCHAN / 4) + c4] = h;
    h.x = fmaf(A.x, h.x, V.x);
    h.y = fmaf(A.y, h.y, V.y);
    h.z = fmaf(A.z, h.z, V.z);
    h.w = fmaf(A.w, h.w, V.w);
  }
}

// pass2: replay each chunk with true carry, 4 channels per thread, float4 out
__global__ void scan_pass2(const uint4* __restrict__ Pav4,
                           const float4* __restrict__ Start, float4* __restrict__ out4)
{
  int tid = blockIdx.x * blockDim.x + threadIdx.x;   // 65536
  int c4 = tid & 1023;
  int chunk = tid >> 10;
  int b = c4 >> 8;
  int d4 = c4 & 255;
  size_t base4 = ((size_t)b * L_SEQ + (size_t)chunk * CH) * (D_DIM / 4) + d4;
  float4 h = Start[(size_t)chunk * (NCHAN / 4) + c4];
#pragma unroll 4
  for (int t = 0; t < CH; ++t) {
    size_t idx = base4 + (size_t)t * (D_DIM / 4);
    uint4 u = Pav4[idx];
    h.x = fmaf(b2f((ushort)(u.x & 0xFFFFu)), h.x, b2f((ushort)(u.x >> 16)));
    h.y = fmaf(b2f((ushort)(u.y & 0xFFFFu)), h.y, b2f((ushort)(u.y >> 16)));
    h.z = fmaf(b2f((ushort)(u.z & 0xFFFFu)), h.z, b2f((ushort)(u.z >> 16)));
    h.w = fmaf(b2f((ushort)(u.w & 0xFFFFu)), h.w, b2f((ushort)(u.w >> 16)));
    out4[idx] = h;
  }
}

extern "C" void kernel_launch(void* const* d_in, const int* in_sizes, int n_in,
                              void* d_out, int out_size, void* d_ws, size_t ws_size,
                              hipStream_t stream) {
  (void)in_sizes; (void)n_in; (void)out_size; (void)ws_size;
  const float* x  = (const float*)d_in[0];
  const float* Wf = (const float*)d_in[1];
  const float* bf = (const float*)d_in[2];
  const float* Wi = (const float*)d_in[3];
  const float* bi = (const float*)d_in[4];
  const float* Wh = (const float*)d_in[5];
  const float* bh = (const float*)d_in[6];

  // workspace (~107 MB)
  ushort* xb  = (ushort*)d_ws;                         // 33.5 MB
  ushort* wfb = xb  + (size_t)M_TOTAL * K_DIM;
  ushort* wib = wfb + (size_t)N_DIM * K_DIM;
  ushort* whb = wib + (size_t)N_DIM * K_DIM;
  uint*  Pav  = (uint*)(whb + (size_t)N_DIM * K_DIM);  // 67 MB packed (a,v)
  float* AggA  = (float*)(Pav + (size_t)M_TOTAL * N_DIM);
  float* AggV  = AggA + NCHAN * NCHUNK;
  float* Start = AggV + NCHAN * NCHUNK;

  cast_f32_bf16<<<(M_TOTAL * K_DIM / 4) / 256, 256, 0, stream>>>(x, xb, M_TOTAL * K_DIM / 4);
  cast_w3<<<dim3((N_DIM * K_DIM / 4) / 256, 3), 256, 0, stream>>>(Wf, Wi, Wh, wfb, wib, whb);

  gemm_fused<<<dim3((M_TOTAL / BM) * (N_DIM / BN)), TPB, 0, stream>>>(
      xb, wfb, wib, whb, bf, bi, bh, Pav);

  scan_pass1<<<(NCHAN / 4 * NCHUNK) / 256, 256, 0, stream>>>(
      (const uint4*)Pav, (float4*)AggA, (float4*)AggV);
  scan_mid<<<(NCHAN / 4) / 256, 256, 0, stream>>>(
      (const float4*)AggA, (const float4*)AggV, (float4*)Start);
  scan_pass2<<<(NCHAN / 4 * NCHUNK) / 256, 256, 0, stream>>>(
      (const uint4*)Pav, (const float4*)Start, (float4*)d_out);
}